// Round 7
// baseline (761.298 us; speedup 1.0000x reference)
//
#include <hip/hip_runtime.h>
#include <hip/hip_bf16.h>
#include <math.h>

// Problem dims (fixed by the reference)
#define BDIM 2
#define SDIM 2048
#define EDIM 768
#define HDIM 12
#define TDIM 128
#define KNN  16
#define FDIM 3072
#define DHD  64
#define BS   (BDIM*SDIM)   // 4096 rows

typedef __attribute__((ext_vector_type(8))) short short8;
typedef __attribute__((ext_vector_type(4))) float f32x4;
typedef __attribute__((ext_vector_type(2))) unsigned u32x2;

// float -> bf16 (RNE); all values here are finite
__device__ __forceinline__ short f2bf(float f) {
  unsigned u = __float_as_uint(f);
  u = u + 0x7fff + ((u >> 16) & 1);
  return (short)(u >> 16);
}
__device__ __forceinline__ float bf2f(short s) {
  return __uint_as_float(((unsigned)(unsigned short)s) << 16);
}
// pack two f32 -> two bf16 (RNE) in one u32 (low = a, high = b)
__device__ __forceinline__ unsigned cvt_pk_bf16(float a, float b) {
  unsigned r;
  asm("v_cvt_pk_bf16_f32 %0, %1, %2" : "=v"(r) : "v"(a), "v"(b));
  return r;
}
// native 2^x
__device__ __forceinline__ float exp2_fast(float x) {
  float r;
  asm("v_exp_f32 %0, %1" : "=v"(r) : "v"(x));
  return r;
}
// async 16B global->LDS; lds base must be wave-uniform (HW adds lane*16)
__device__ __forceinline__ void cp16(void* lds, const void* g) {
  __builtin_amdgcn_global_load_lds(
      (const __attribute__((address_space(1))) unsigned int*)g,
      (__attribute__((address_space(3))) unsigned int*)lds, 16, 0, 0);
}

// ---------------------------------------------------------------------------
// block-wide sum reduction of two values (256 threads = 4 waves)
// ---------------------------------------------------------------------------
__device__ __forceinline__ void block_reduce_sum2(float& a, float& b) {
  __shared__ float sa[4], sb[4];
  #pragma unroll
  for (int off = 32; off > 0; off >>= 1) {
    a += __shfl_xor(a, off);
    b += __shfl_xor(b, off);
  }
  int wid = threadIdx.x >> 6;
  if ((threadIdx.x & 63) == 0) { sa[wid] = a; sb[wid] = b; }
  __syncthreads();
  a = sa[0] + sa[1] + sa[2] + sa[3];
  b = sb[0] + sb[1] + sb[2] + sb[3];
}

// ---------------------------------------------------------------------------
// merged weight transpose+convert: 8 segments, one launch.
// W [K][N] fp32 -> Wt [N][K] bf16, 64x64 tiles.
// ---------------------------------------------------------------------------
struct WcSeg { const float* src; short* dst; int K, N, ntx, start; };
struct WcArgs { WcSeg s[8]; };

__global__ __launch_bounds__(256) void wconv_all(WcArgs a) {
  __shared__ float tile[64][65];
  const int bid = blockIdx.x;
  int si = 0;
  #pragma unroll
  for (int i = 1; i < 8; ++i) if (bid >= a.s[i].start) si = i;
  const float* W = a.s[si].src;
  short* Wt = a.s[si].dst;
  const int K = a.s[si].K, N = a.s[si].N;
  const int t = bid - a.s[si].start;
  const int n0 = (t % a.s[si].ntx)*64, k0 = (t / a.s[si].ntx)*64;
  const int tid = threadIdx.x;
  for (int i = tid; i < 4096; i += 256) {
    int r = i>>6, c = i&63;
    tile[r][c] = W[(size_t)(k0+r)*N + n0 + c];
  }
  __syncthreads();
  for (int i = tid; i < 4096; i += 256) {
    int r = i>>6, c = i&63;
    Wt[(size_t)(n0+r)*K + k0 + c] = f2bf(tile[c][r]);
  }
}

// ---------------------------------------------------------------------------
// V pre-transpose: qkv[:,1536+h*64+d] -> vt[(b*H+h)*64+d][s]  (bf16)
// grid (SDIM/64, BDIM*HDIM)
// ---------------------------------------------------------------------------
__global__ __launch_bounds__(256) void vtrans_kernel(
    const short* __restrict__ qkv, short* __restrict__ vt) {
  __shared__ short t[64][72];
  const int s0 = blockIdx.x*64;
  const int bh = blockIdx.y;
  const int b = bh / HDIM, h = bh % HDIM;
  const int tid = threadIdx.x;
  for (int i = tid; i < 512; i += 256) {
    int r = i>>3, c8 = (i&7)<<3;
    *(short8*)&t[r][c8] =
        *(const short8*)&qkv[(size_t)(b*SDIM+s0+r)*2304 + 1536 + h*DHD + c8];
  }
  __syncthreads();
  for (int i = tid; i < 512; i += 256) {
    int d = i>>3, c8 = (i&7)<<3;
    short8 pk;
    #pragma unroll
    for (int j = 0; j < 8; ++j) pk[j] = t[c8+j][d];
    *(short8*)&vt[(size_t)(bh*DHD+d)*SDIM + s0 + c8] = pk;
  }
}

// ---------------------------------------------------------------------------
// h_bf = bf16(h); hn hi/lo bf16 split; x = LN(h) (fp32 + bf16)
// ---------------------------------------------------------------------------
__global__ __launch_bounds__(256) void norm_ln1_kernel(
    const float* __restrict__ h, const float* __restrict__ s,
    const float* __restrict__ bb, short* __restrict__ hb,
    short* __restrict__ hh, short* __restrict__ hl,
    float* __restrict__ x, short* __restrict__ xb) {
  int row = blockIdx.x;
  const float* hr = h + (size_t)row * EDIM;
  float v[3], s1 = 0.f, s2 = 0.f;
  #pragma unroll
  for (int t = 0; t < 3; ++t) {
    v[t] = hr[threadIdx.x + 256*t];
    s1 += v[t]; s2 += v[t]*v[t];
  }
  block_reduce_sum2(s1, s2);
  float mu  = s1 * (1.f/EDIM);
  float var = s2 * (1.f/EDIM) - mu*mu;
  float rs  = rsqrtf(var + 1e-6f);
  float invn = 1.f / (sqrtf(s2) + 1e-8f);
  #pragma unroll
  for (int t = 0; t < 3; ++t) {
    int i = threadIdx.x + 256*t;
    size_t idx = (size_t)row*EDIM + i;
    hb[idx] = f2bf(v[t]);
    float hnv = v[t]*invn;
    short hi = f2bf(hnv);
    hh[idx] = hi;
    hl[idx] = f2bf(hnv - bf2f(hi));
    float xv = (v[t]-mu)*rs*s[i] + bb[i];
    x[idx] = xv;
    xb[idx] = f2bf(xv);
  }
}

// ---------------------------------------------------------------------------
// LN -> bf16 out only
// ---------------------------------------------------------------------------
__global__ __launch_bounds__(256) void ln_bf_kernel(
    const float* __restrict__ in, const float* __restrict__ s,
    const float* __restrict__ bb, short* __restrict__ outb) {
  int row = blockIdx.x;
  const float* r = in + (size_t)row * EDIM;
  float v[3], s1 = 0.f, s2 = 0.f;
  #pragma unroll
  for (int t = 0; t < 3; ++t) {
    v[t] = r[threadIdx.x + 256*t];
    s1 += v[t]; s2 += v[t]*v[t];
  }
  block_reduce_sum2(s1, s2);
  float mu  = s1 * (1.f/EDIM);
  float var = s2 * (1.f/EDIM) - mu*mu;
  float rs  = rsqrtf(var + 1e-6f);
  #pragma unroll
  for (int t = 0; t < 3; ++t) {
    int i = threadIdx.x + 256*t;
    outb[(size_t)row*EDIM + i] = f2bf((v[t]-mu)*rs*s[i] + bb[i]);
  }
}

// ---------------------------------------------------------------------------
// bf16 MFMA GEMM with 2-phase double-buffered pipeline (T3-lite):
// 128x128 tile, BK=64, 256 thr = 4 waves (2x2), wave tile 64x64.
// A [M][K] bf16 (lda=K), Wt [N][K] bf16. LDS [128][64] with slot^(row&7)
// XOR swizzle, staged via global_load_lds; next tile's loads issued BEFORE
// computing the current tile (latency hides under MFMA even at 1 block/CU).
// ACT: 0 none, 2 gelu(tanh), 3 sigmoid-blend. OUTBF: bf16 vs fp32 out.
// ---------------------------------------------------------------------------
template<int ACT, int OUTBF>
__global__ __launch_bounds__(256) void gemm_mfma(
    const short* __restrict__ A, const short* __restrict__ Wt,
    const float* __restrict__ bias, const float* res,
    float* Cf, short* Cb, int Cb_ld,
    const float* __restrict__ blc, const float* __restrict__ blx,
    int K, int N) {
  __shared__ __align__(16) short As[2][128*64];
  __shared__ __align__(16) short Bs[2][128*64];
  const int bm = blockIdx.y*128, bn = blockIdx.x*128;
  const int tid = threadIdx.x;
  const int w = tid>>6, lane = tid&63, l15 = lane&15, g = lane>>4;
  const int wm = (w>>1)*64, wn = (w&1)*64;
  f32x4 acc[4][4] = {};

  auto stage = [&](int buf, int k0) {
    #pragma unroll
    for (int it = 0; it < 4; ++it) {
      int p = (it*256 + tid)*16;          // byte pos in linear 16KB tile
      int row = p >> 7;
      int ss = ((p >> 4) & 7) ^ (row & 7);
      cp16((char*)&As[buf][0] + it*4096 + w*1024, A  + (size_t)(bm+row)*K + k0 + ss*8);
      cp16((char*)&Bs[buf][0] + it*4096 + w*1024, Wt + (size_t)(bn+row)*K + k0 + ss*8);
    }
  };

  const int nk = K >> 6;
  stage(0, 0);
  __syncthreads();                        // drains vmcnt before first compute
  for (int t = 0; t < nk; ++t) {
    const int cur = t & 1;
    if (t + 1 < nk) stage(cur ^ 1, (t+1) << 6);   // prefetch next tile
    #pragma unroll
    for (int ks = 0; ks < 2; ++ks) {
      short8 af[4], bfv[4];
      #pragma unroll
      for (int mt = 0; mt < 4; ++mt) {
        int r = wm + mt*16 + l15;
        af[mt] = *(const short8*)&As[cur][r*64 + (((ks*4+g) ^ (r&7))*8)];
      }
      #pragma unroll
      for (int nt = 0; nt < 4; ++nt) {
        int r = wn + nt*16 + l15;
        bfv[nt] = *(const short8*)&Bs[cur][r*64 + (((ks*4+g) ^ (r&7))*8)];
      }
      #pragma unroll
      for (int mt = 0; mt < 4; ++mt)
        #pragma unroll
        for (int nt = 0; nt < 4; ++nt)
          acc[mt][nt] = __builtin_amdgcn_mfma_f32_16x16x32_bf16(af[mt], bfv[nt], acc[mt][nt], 0, 0, 0);
    }
    __syncthreads();                      // waits vmcnt(0) -> next tile ready
  }
  #pragma unroll
  for (int mt = 0; mt < 4; ++mt) {
    #pragma unroll
    for (int nt = 0; nt < 4; ++nt) {
      #pragma unroll
      for (int reg = 0; reg < 4; ++reg) {
        int row = bm + wm + mt*16 + g*4 + reg;
        int col = bn + wn + nt*16 + l15;
        float v = acc[mt][nt][reg];
        if (bias) v += bias[col];
        if (ACT == 2) {
          float xx = v;
          float t2 = 0.7978845608028654f*(xx + 0.044715f*xx*xx*xx);
          v = 0.5f*xx*(1.f + tanhf(t2));
        }
        if (ACT == 3) {
          float gg = 1.f/(1.f + expf(-v));
          size_t ix = (size_t)row*EDIM + col;     // N == EDIM for gate
          float mv = gg*blc[ix] + (1.f-gg)*blx[ix];
          Cb[(size_t)row*Cb_ld + col] = f2bf(mv);
        } else {
          if (res) v += res[(size_t)row*N + col];
          if (OUTBF) Cb[(size_t)row*Cb_ld + col] = f2bf(v);
          else       Cf[(size_t)row*N + col] = v;
        }
      }
    }
  }
}

// ---------------------------------------------------------------------------
// dist = 1 - hn@hn^T via hi/lo bf16 split (3 MFMA products), 128x128 tiles,
// 2-phase double-buffered like gemm_mfma (128 KB LDS). diag = 1e9. Per-batch.
// ---------------------------------------------------------------------------
__global__ __launch_bounds__(256) void dist_mfma(
    const short* __restrict__ Hh, const short* __restrict__ Hl,
    float* __restrict__ dist) {
  __shared__ __align__(16) short Ah[2][128*64], Al[2][128*64];
  __shared__ __align__(16) short Bh[2][128*64], Bl[2][128*64];
  const int bm = blockIdx.y*128, bn = blockIdx.x*128;
  const int tid = threadIdx.x;
  const int w = tid>>6, lane = tid&63, l15 = lane&15, g = lane>>4;
  const int wm = (w>>1)*64, wn = (w&1)*64;
  f32x4 acc[4][4] = {};

  auto stage = [&](int buf, int k0) {
    #pragma unroll
    for (int it = 0; it < 4; ++it) {
      int p = (it*256 + tid)*16;
      int row = p >> 7;
      int ss = ((p >> 4) & 7) ^ (row & 7);
      size_t ga = (size_t)(bm+row)*EDIM + k0 + ss*8;
      size_t gb = (size_t)(bn+row)*EDIM + k0 + ss*8;
      cp16((char*)&Ah[buf][0] + it*4096 + w*1024, Hh + ga);
      cp16((char*)&Al[buf][0] + it*4096 + w*1024, Hl + ga);
      cp16((char*)&Bh[buf][0] + it*4096 + w*1024, Hh + gb);
      cp16((char*)&Bl[buf][0] + it*4096 + w*1024, Hl + gb);
    }
  };

  const int nk = EDIM >> 6;   // 12
  stage(0, 0);
  __syncthreads();
  for (int t = 0; t < nk; ++t) {
    const int cur = t & 1;
    if (t + 1 < nk) stage(cur ^ 1, (t+1) << 6);
    #pragma unroll
    for (int ks = 0; ks < 2; ++ks) {
      short8 ah[4], al[4], bh[4], bl[4];
      #pragma unroll
      for (int mt = 0; mt < 4; ++mt) {
        int r = wm + mt*16 + l15;
        int o = r*64 + (((ks*4+g) ^ (r&7))*8);
        ah[mt] = *(const short8*)&Ah[cur][o];
        al[mt] = *(const short8*)&Al[cur][o];
      }
      #pragma unroll
      for (int nt = 0; nt < 4; ++nt) {
        int r = wn + nt*16 + l15;
        int o = r*64 + (((ks*4+g) ^ (r&7))*8);
        bh[nt] = *(const short8*)&Bh[cur][o];
        bl[nt] = *(const short8*)&Bl[cur][o];
      }
      #pragma unroll
      for (int mt = 0; mt < 4; ++mt)
        #pragma unroll
        for (int nt = 0; nt < 4; ++nt) {
          acc[mt][nt] = __builtin_amdgcn_mfma_f32_16x16x32_bf16(ah[mt], bh[nt], acc[mt][nt], 0, 0, 0);
          acc[mt][nt] = __builtin_amdgcn_mfma_f32_16x16x32_bf16(ah[mt], bl[nt], acc[mt][nt], 0, 0, 0);
          acc[mt][nt] = __builtin_amdgcn_mfma_f32_16x16x32_bf16(al[mt], bh[nt], acc[mt][nt], 0, 0, 0);
        }
    }
    __syncthreads();
  }
  #pragma unroll
  for (int mt = 0; mt < 4; ++mt) {
    #pragma unroll
    for (int nt = 0; nt < 4; ++nt) {
      #pragma unroll
      for (int reg = 0; reg < 4; ++reg) {
        int row = bm + wm + mt*16 + g*4 + reg;
        int col = bn + wn + nt*16 + l15;
        float v = 1.f - acc[mt][nt][reg];
        if (row == col) v = 1e9f;
        dist[(size_t)row*SDIM + col] = v;
      }
    }
  }
}

// ---------------------------------------------------------------------------
// per-row top-16 (stable ties -> smaller idx), softmax(-nd), combined.
// values cached in registers; per pass only a shuffle-reduce + owner rescan.
// ---------------------------------------------------------------------------
__global__ __launch_bounds__(256) void topk_kernel(
    const float* __restrict__ dist, const float* __restrict__ topob,
    float* __restrict__ combb) {
  int s = blockIdx.x;
  __shared__ float wbv[4];
  __shared__ int   wbi[4];
  __shared__ float nd[KNN];
  __shared__ int   nidx[KNN];
  __shared__ float wts[KNN];
  const int tid = threadIdx.x, lane = tid & 63, wid = tid >> 6;
  const float* drow = dist + (size_t)s*SDIM;
  float lv[8];
  float best = 3e38f; int bidx = 1<<30;
  #pragma unroll
  for (int j = 0; j < 8; ++j) {
    int i = tid + j*256;
    float v = drow[i];
    lv[j] = v;
    if (v < best) { best = v; bidx = i; }
  }
  for (int pass = 0; pass < KNN; ++pass) {
    float bv = best; int bi = bidx;
    #pragma unroll
    for (int off = 32; off > 0; off >>= 1) {
      float ov = __shfl_xor(bv, off);
      int   oi = __shfl_xor(bi, off);
      if (ov < bv || (ov == bv && oi < bi)) { bv = ov; bi = oi; }
    }
    if (lane == 0) { wbv[wid] = bv; wbi[wid] = bi; }
    __syncthreads();
    if (tid == 0) {
      float fv = wbv[0]; int fi = wbi[0];
      #pragma unroll
      for (int q2 = 1; q2 < 4; ++q2)
        if (wbv[q2] < fv || (wbv[q2] == fv && wbi[q2] < fi)) { fv = wbv[q2]; fi = wbi[q2]; }
      nd[pass] = fv; nidx[pass] = fi;
    }
    __syncthreads();
    int wi = nidx[pass];
    if ((wi & 255) == tid) {
      int jj = wi >> 8;
      #pragma unroll
      for (int j = 0; j < 8; ++j) if (j == jj) lv[j] = 3e38f;
      best = 3e38f; bidx = 1<<30;
      #pragma unroll
      for (int j = 0; j < 8; ++j)
        if (lv[j] < best) { best = lv[j]; bidx = tid + j*256; }
    }
    __syncthreads();
  }
  if (tid == 0) {
    float m = -nd[0];
    for (int k2 = 1; k2 < KNN; ++k2) m = fmaxf(m, -nd[k2]);
    float ssum = 0.f;
    for (int k2 = 0; k2 < KNN; ++k2) { float e = expf(-nd[k2] - m); wts[k2] = e; ssum += e; }
    float inv = 1.f/ssum;
    for (int k2 = 0; k2 < KNN; ++k2) wts[k2] *= inv;
  }
  __syncthreads();
  if (tid < TDIM) {
    float acc = topob[(size_t)s*TDIM + tid];
    #pragma unroll
    for (int k2 = 0; k2 < KNN; ++k2) acc += wts[k2]*topob[(size_t)nidx[k2]*TDIM + tid];
    combb[(size_t)s*TDIM + tid] = acc;
  }
}

// ---------------------------------------------------------------------------
// fused topo-MLP per row (fp32), writes pf as bf16 into cat[:, 768:896]
// ---------------------------------------------------------------------------
__global__ __launch_bounds__(256) void topo_mlp_kernel(
    const float* __restrict__ comb,
    const float* __restrict__ W1, const float* __restrict__ b1,
    const float* __restrict__ W2, const float* __restrict__ b2,
    const float* __restrict__ lns, const float* __restrict__ lnb,
    const float* __restrict__ Wp1, const float* __restrict__ bp1,
    const float* __restrict__ Wp2, const float* __restrict__ bp2,
    short* __restrict__ cat) {
  int row = blockIdx.x;
  __shared__ float c[TDIM], a1[2*TDIM], t2[TDIM];
  __shared__ float red[8];
  const int tid = threadIdx.x;
  if (tid < TDIM) c[tid] = comb[(size_t)row*TDIM + tid];
  __syncthreads();
  {
    float a = b1[tid];
    for (int i = 0; i < TDIM; ++i) a += c[i]*W1[i*2*TDIM + tid];
    a1[tid] = fmaxf(a, 0.f);
  }
  __syncthreads();
  float tval = 0.f;
  if (tid < TDIM) {
    float a = b2[tid];
    for (int i = 0; i < 2*TDIM; ++i) a += a1[i]*W2[i*TDIM + tid];
    tval = a;
  }
  float s1 = (tid < TDIM) ? tval : 0.f;
  float s2 = (tid < TDIM) ? tval*tval : 0.f;
  #pragma unroll
  for (int off = 32; off > 0; off >>= 1) { s1 += __shfl_xor(s1, off); s2 += __shfl_xor(s2, off); }
  if ((tid & 63) == 0) { red[tid>>6] = s1; red[4 + (tid>>6)] = s2; }
  __syncthreads();
  s1 = red[0]+red[1]+red[2]+red[3];
  s2 = red[4]+red[5]+red[6]+red[7];
  float mu  = s1 * (1.f/TDIM);
  float var = s2 * (1.f/TDIM) - mu*mu;
  float rs  = rsqrtf(var + 1e-6f);
  if (tid < TDIM) t2[tid] = (tval - mu)*rs*lns[tid] + lnb[tid];
  __syncthreads();
  if (tid < TDIM) {
    float a = bp1[tid];
    for (int i = 0; i < TDIM; ++i) a += t2[i]*Wp1[i*TDIM + tid];
    a1[tid] = fmaxf(a, 0.f);
  }
  __syncthreads();
  if (tid < TDIM) {
    float a = bp2[tid];
    for (int i = 0; i < TDIM; ++i) a += a1[i]*Wp2[i*TDIM + tid];
    cat[(size_t)row*896 + 768 + tid] = f2bf(a);
  }
}

// ---------------------------------------------------------------------------
// MFMA flash attention v3: swapped QK^T (S^T = mfma(K,Q)) -> per-lane q-row,
// in-lane softmax (log2 domain, exp2), defer-max (THR=8), packed P stores.
// grid (S/64, H, B), 256 thr = 4 waves; wave owns 16 q rows; KT=128.
// ---------------------------------------------------------------------------
__global__ __launch_bounds__(256) void attn_mfma(
    const short* __restrict__ qkv, const short* __restrict__ vtb,
    const int* __restrict__ maskp,
    float* __restrict__ ctx, short* __restrict__ ctxb) {
  __shared__ __align__(16) short Ks[128*64];     // [krow][d]   8-slot swizzle
  __shared__ __align__(16) short Vs[64*128];     // [d][krow]  16-slot swizzle
  __shared__ __align__(16) short Ps[4*16*128];   // per-wave [q][k], slot^((q&7)<<1)
  __shared__ float Ms[128];
  const float SCL = 0.18033688011112042f;        // 0.125 * log2(e)
  const float MASKVAL = -14426.950408889634f;    // -10000 * log2(e)
  const int qb0 = blockIdx.x*64;
  const int hh = blockIdx.y, b = blockIdx.z;
  const int bh = b*HDIM + hh;
  const int tid = threadIdx.x;
  const int w = tid>>6, lane = tid&63, l15 = lane&15, g = lane>>4;
  short8 qf[2];
  {
    size_t rbase = (size_t)(b*SDIM + qb0 + w*16 + l15)*2304 + hh*DHD;
    qf[0] = *(const short8*)&qkv[rbase + g*8];
    qf[1] = *(const short8*)&qkv[rbase + 32 + g*8];
  }
  f32x4 acc[4] = {};
  float m_run = -1e30f, l_run = 0.f;
  char* PsW = (char*)Ps + w*4096 + l15*256;      // this lane's q-row base
  const int swz = (l15 & 7) << 1;                 // slot XOR (8B slots)
  for (int kt = 0; kt < SDIM; kt += 128) {
    // K tile: 128 rows x 64 d
    #pragma unroll
    for (int it = 0; it < 4; ++it) {
      int t = it*256 + tid;
      int row = t>>3, slot = t&7, ss = slot ^ (row&7);
      cp16((char*)Ks + it*4096 + w*1024,
           qkv + (size_t)(b*SDIM+kt+row)*2304 + 768 + hh*DHD + ss*8);
    }
    // V^T tile: 64 d-rows x 128 s
    #pragma unroll
    for (int it = 0; it < 4; ++it) {
      int t = it*256 + tid;
      int row = t>>4, slot = t&15, ss = slot ^ (row&15);
      cp16((char*)Vs + it*4096 + w*1024,
           vtb + (size_t)(bh*DHD+row)*SDIM + kt + ss*8);
    }
    if (tid < 128) Ms[tid] = (float)maskp[b*SDIM + kt + tid];
    __syncthreads();
    // S^T = K @ Q^T : lane holds k = ct*16+g*4+reg, q = l15
    f32x4 s[8] = {};
    #pragma unroll
    for (int ks = 0; ks < 2; ++ks) {
      #pragma unroll
      for (int ct = 0; ct < 8; ++ct) {
        int r = ct*16 + l15;
        short8 kb8 = *(const short8*)&Ks[r*64 + (((ks*4+g) ^ (r&7))*8)];
        s[ct] = __builtin_amdgcn_mfma_f32_16x16x32_bf16(kb8, qf[ks], s[ct], 0, 0, 0);
      }
    }
    // scale (log2 domain) + mask + row max
    float rm = -1e30f;
    #pragma unroll
    for (int ct = 0; ct < 8; ++ct) {
      float4 mk = *(const float4*)&Ms[ct*16 + g*4];
      float v0 = s[ct][0]*SCL; if (mk.x == 0.f) v0 = MASKVAL;
      float v1 = s[ct][1]*SCL; if (mk.y == 0.f) v1 = MASKVAL;
      float v2 = s[ct][2]*SCL; if (mk.z == 0.f) v2 = MASKVAL;
      float v3 = s[ct][3]*SCL; if (mk.w == 0.f) v3 = MASKVAL;
      s[ct][0] = v0; s[ct][1] = v1; s[ct][2] = v2; s[ct][3] = v3;
      rm = fmaxf(rm, fmaxf(fmaxf(v0, v1), fmaxf(v2, v3)));
    }
    rm = fmaxf(rm, __shfl_xor(rm, 16));
    rm = fmaxf(rm, __shfl_xor(rm, 32));
    // defer-max: only rescale when some row grew past THR (=8/ln2)
    if (__any(rm > m_run + 11.5415603f)) {
      float mnew = fmaxf(m_run, rm);
      float corr = exp2_fast(m_run - mnew);
      l_run *= corr;
      #pragma unroll
      for (int reg = 0; reg < 4; ++reg) {
        float cq = __shfl(corr, (g<<4) | (g*4 + reg));
        #pragma unroll
        for (int dt = 0; dt < 4; ++dt) acc[dt][reg] *= cq;
      }
      m_run = mnew;
    }
    // P = exp2(s - m), in-lane sum, packed store to per-wave P buffer
    float rs = 0.f;
    #pragma unroll
    for (int ct = 0; ct < 8; ++ct) {
      float p0 = exp2_fast(s[ct][0] - m_run);
      float p1 = exp2_fast(s[ct][1] - m_run);
      float p2 = exp2_fast(s[ct][2] - m_run);
      float p3 = exp2_fast(s[ct][3] - m_run);
      rs += (p0 + p1) + (p2 + p3);
      u32x2 pk;
      pk.x = cvt_pk_bf16(p0, p1);
      pk.y = cvt_pk_bf16(p2, p3);
      int slot = ct*4 + g;                       // k-quad index
      *(u32x2*)(PsW + ((slot ^ swz) << 3)) = pk;
    }
    rs += __shfl_xor(rs, 16);
    rs += __shfl_xor(rs, 32);
    l_run += rs;
    // ctx += P @ V : P read back as A-frag from per-wave buffer
    #pragma unroll
    for (int ks2 = 0; ks2 < 4; ++ks2) {
      int s0 = ks2*8 + g*2;
      short8 pa = *(const short8*)(PsW + ((s0 ^ swz) << 3));
      #pragma unroll
      for (int dt = 0; dt < 4; ++dt) {
        int r = dt*16 + l15;
        short8 vb8 = *(const short8*)&Vs[r*128 + (((ks2*4+g) ^ (r&15))*8)];
        acc[dt] = __builtin_amdgcn_mfma_f32_16x16x32_bf16(pa, vb8, acc[dt], 0, 0, 0);
      }
    }
    __syncthreads();
  }
  float invq[4];
  #pragma unroll
  for (int reg = 0; reg < 4; ++reg)
    invq[reg] = 1.f / __shfl(l_run, (g<<4) | (g*4 + reg));
  #pragma unroll
  for (int dt = 0; dt < 4; ++dt) {
    #pragma unroll
    for (int reg = 0; reg < 4; ++reg) {
      int row = b*SDIM + qb0 + w*16 + g*4 + reg;
      float v = acc[dt][reg]*invq[reg];
      ctx [(size_t)row*EDIM + hh*DHD + dt*16 + l15] = v;
      ctxb[(size_t)row*896  + hh*DHD + dt*16 + l15] = f2bf(v);
    }
  }
}

// ---------------------------------------------------------------------------
extern "C" void kernel_launch(void* const* d_in, const int* in_sizes, int n_in,
                              void* d_out, int out_size, void* d_ws, size_t ws_size,
                              hipStream_t stream) {
  const float* h      = (const float*)d_in[0];
  const int*   mask   = (const int*)  d_in[1];
  const float* W_topo = (const float*)d_in[2];
  const float* b_topo = (const float*)d_in[3];
  const float* W_m1   = (const float*)d_in[4];
  const float* b_m1   = (const float*)d_in[5];
  const float* W_m2   = (const float*)d_in[6];
  const float* b_m2   = (const float*)d_in[7];
  const float* ln_t_s = (const float*)d_in[8];
  const float* ln_t_b = (const float*)d_in[9];
  const float* W_p1   = (const float*)d_in[10];
  const float* b_p1   = (const float*)d_in[11];
  const float* W_p2   = (const float*)d_in[12];
  const float* b_p2   = (const float*)d_in[13];
  const float* ln1_s  = (const float*)d_in[14];
  const float* ln1_b  = (const float*)d_in[15];
  const float* Wq     = (const float*)d_in[16];
  const float* Wk     = (const float*)d_in[17];
  const float* Wv     = (const float*)d_in[18];
  const float* W_gate = (const float*)d_in[19];
  const float* b_gate = (const float*)d_in[20];
  const float* W_o    = (const float*)d_in[21];
  const float* b_o    = (const float*)d_in[22];
  const float* ln2_s  = (const float*)d_in[23];
  const float* ln2_b  = (const float*)d_in[24];
  const float* W_f1   = (const float*)d_in[25];
  const float* b_f1   = (const float*)d_in[26];
  const float* W_f2   = (const float*)d_in[27];
  const float* b_f2   = (const float*)d_in[28];
  float* out = (float*)d_out;

  // ---- workspace layout (~90 MB) ----
  const size_t R = (size_t)BS*EDIM;    // 3,145,728 elements
  short* wt_topo = (short*)d_ws;                       // [128][768]
  short* wt_qkv  = wt_topo + (size_t)128*768;          // [2304][768]
  short* wt_g    = wt_qkv  + (size_t)2304*768;         // [768][896]
  short* wt_o    = wt_g    + (size_t)768*896;          // [768][768]
  short* wt_f1   = wt_o    + (size_t)768*768;          // [3072][768]
  short* wt_f2   = wt_f1   + (size_t)3072*768;         // [768][3072]
  short* regA    = wt_f2   + (size_t)768*3072;         // R: h_bf -> mixb
  short* regBCE  = regA + R;                           // 3R: hn_hi|hn_lo|E -> qkv
  short* regD    = regBCE + 3*R;                       // R: x_bf -> y_bf
  short* cat     = regD + R;                           // BS*896: [ctx_bf | pf_bf]
  float* xf      = (float*)(cat + (size_t)BS*896);     // R fp32: post-LN x
  float* Ff      = xf + R;                             // 16.8MB: dist / ctx / ybuf
  short* vtb     = (short*)(Ff + (size_t)SDIM*SDIM);   // R shorts: V^T per (b,h)

  short* h_bf  = regA;
  short* mixb  = regA;
  short* hn_hi = regBCE;
  short* hn_lo = regBCE + R;
  float* topo  = (float*)(regBCE + 2*R);
  float* comb  = topo + (size_t)BS*TDIM;
  short* qkvb  = regBCE;
  short* x_bf  = regD;
  short* y_bf  = regD;
  float* dbuf  = Ff;
  float* ctxf  = Ff;
  short* ybuf  = (short*)Ff;

  // P0: all weight transposes+converts in ONE launch (1920 tiles)
  WcArgs wa;
  wa.s[0] = {W_topo, wt_topo,                    EDIM, TDIM,  TDIM/64, 0};
  wa.s[1] = {Wq,     wt_qkv,                     EDIM, EDIM,  EDIM/64, 24};
  wa.s[2] = {Wk,     wt_qkv + (size_t)768*768,   EDIM, EDIM,  EDIM/64, 168};
  wa.s[3] = {Wv,     wt_qkv + (size_t)1536*768,  EDIM, EDIM,  EDIM/64, 312};
  wa.s[4] = {W_gate, wt_g,                       896,  EDIM,  EDIM/64, 456};
  wa.s[5] = {W_o,    wt_o,                       EDIM, EDIM,  EDIM/64, 624};
  wa.s[6] = {W_f1,   wt_f1,                      EDIM, FDIM,  FDIM/64, 768};
  wa.s[7] = {W_f2,   wt_f2,                      FDIM, EDIM,  EDIM/64, 1344};
  wconv_all<<<1920, 256, 0, stream>>>(wa);
  // P1: h_bf + hn hi/lo + LN1 (fp32 + bf16)
  norm_ln1_kernel<<<BS, 256, 0, stream>>>(h, ln1_s, ln1_b, h_bf, hn_hi, hn_lo, xf, x_bf);
  // P2: topo = h @ W_topo + b_topo (fp32 out)
  gemm_mfma<0,0><<<dim3(1, BS/128), 256, 0, stream>>>(
      h_bf, wt_topo, b_topo, nullptr, topo, nullptr, 0, nullptr, nullptr, EDIM, TDIM);
  // P3: per-batch dist + topk + combined
  for (int b = 0; b < BDIM; ++b) {
    dist_mfma<<<dim3(SDIM/128, SDIM/128), 256, 0, stream>>>(
        hn_hi + (size_t)b*SDIM*EDIM, hn_lo + (size_t)b*SDIM*EDIM, dbuf);
    topk_kernel<<<SDIM, 256, 0, stream>>>(
        dbuf, topo + (size_t)b*SDIM*TDIM, comb + (size_t)b*SDIM*TDIM);
  }
  // P4: topo MLP -> pf bf16 into cat[:,768:]
  topo_mlp_kernel<<<BS, 256, 0, stream>>>(comb, W_m1, b_m1, W_m2, b_m2,
                                          ln_t_s, ln_t_b, W_p1, b_p1, W_p2, b_p2, cat);
  // P5: fused QKV (N=2304, bf16 out; overwrites regBCE after topo/comb dead)
  gemm_mfma<0,1><<<dim3(2304/128, BS/128), 256, 0, stream>>>(
      x_bf, wt_qkv, nullptr, nullptr, nullptr, qkvb, 2304, nullptr, nullptr, EDIM, 2304);
  // P5b: V pre-transpose for attention
  vtrans_kernel<<<dim3(SDIM/64, BDIM*HDIM), 256, 0, stream>>>(qkvb, vtb);
  // P6: attention -> ctx fp32 (Ff) + ctx bf16 (cat[:,0:768])
  attn_mfma<<<dim3(SDIM/64, HDIM, BDIM), 256, 0, stream>>>(qkvb, vtb, mask, ctxf, cat);
  // P7: gate GEMM (K=896) with fused sigmoid-blend -> mixb bf16
  gemm_mfma<3,1><<<dim3(EDIM/128, BS/128), 256, 0, stream>>>(
      cat, wt_g, b_gate, nullptr, nullptr, mixb, EDIM, ctxf, xf, 896, EDIM);
  // P8: h2 = h + mix @ W_o + b_o -> out
  gemm_mfma<0,0><<<dim3(EDIM/128, BS/128), 256, 0, stream>>>(
      mixb, wt_o, b_o, h, out, nullptr, 0, nullptr, nullptr, EDIM, EDIM);
  // P9: y = LN2(h2) -> y_bf
  ln_bf_kernel<<<BS, 256, 0, stream>>>(out, ln2_s, ln2_b, y_bf);
  // P10: yF = gelu(y @ W_f1 + b_f1) -> ybuf bf16
  gemm_mfma<2,1><<<dim3(FDIM/128, BS/128), 256, 0, stream>>>(
      y_bf, wt_f1, b_f1, nullptr, nullptr, ybuf, FDIM, nullptr, nullptr, EDIM, FDIM);
  // P11: out = h2 + yF @ W_f2 + b_f2 (in place)
  gemm_mfma<0,0><<<dim3(EDIM/128, BS/128), 256, 0, stream>>>(
      ybuf, wt_f2, b_f2, out, out, nullptr, 0, nullptr, nullptr, FDIM, EDIM);
}

// Round 9
// 623.912 us; speedup vs baseline: 1.2202x; 1.2202x over previous
//
#include <hip/hip_runtime.h>
#include <hip/hip_bf16.h>
#include <math.h>

// Problem dims (fixed by the reference)
#define BDIM 2
#define SDIM 2048
#define EDIM 768
#define HDIM 12
#define TDIM 128
#define KNN  16
#define FDIM 3072
#define DHD  64
#define BS   (BDIM*SDIM)   // 4096 rows

typedef __attribute__((ext_vector_type(8))) short short8;
typedef __attribute__((ext_vector_type(4))) float f32x4;
typedef __attribute__((ext_vector_type(2))) unsigned u32x2;

// float -> bf16 (RNE); all values here are finite
__device__ __forceinline__ short f2bf(float f) {
  unsigned u = __float_as_uint(f);
  u = u + 0x7fff + ((u >> 16) & 1);
  return (short)(u >> 16);
}
__device__ __forceinline__ float bf2f(short s) {
  return __uint_as_float(((unsigned)(unsigned short)s) << 16);
}
// pack two f32 -> two bf16 (RNE) in one u32 (low = a, high = b)
__device__ __forceinline__ unsigned cvt_pk_bf16(float a, float b) {
  unsigned r;
  asm("v_cvt_pk_bf16_f32 %0, %1, %2" : "=v"(r) : "v"(a), "v"(b));
  return r;
}
// native 2^x
__device__ __forceinline__ float exp2_fast(float x) {
  float r;
  asm("v_exp_f32 %0, %1" : "=v"(r) : "v"(x));
  return r;
}
// async 16B global->LDS; lds base must be wave-uniform (HW adds lane*16)
__device__ __forceinline__ void cp16(void* lds, const void* g) {
  __builtin_amdgcn_global_load_lds(
      (const __attribute__((address_space(1))) unsigned int*)g,
      (__attribute__((address_space(3))) unsigned int*)lds, 16, 0, 0);
}

// ---------------------------------------------------------------------------
// block-wide sum reduction of two values (256 threads = 4 waves)
// ---------------------------------------------------------------------------
__device__ __forceinline__ void block_reduce_sum2(float& a, float& b) {
  __shared__ float sa[4], sb[4];
  #pragma unroll
  for (int off = 32; off > 0; off >>= 1) {
    a += __shfl_xor(a, off);
    b += __shfl_xor(b, off);
  }
  int wid = threadIdx.x >> 6;
  if ((threadIdx.x & 63) == 0) { sa[wid] = a; sb[wid] = b; }
  __syncthreads();
  a = sa[0] + sa[1] + sa[2] + sa[3];
  b = sb[0] + sb[1] + sb[2] + sb[3];
}

// ---------------------------------------------------------------------------
// merged weight transpose+convert: 8 segments, one launch.
// W [K][N] fp32 -> Wt [N][K] bf16, 64x64 tiles.
// ---------------------------------------------------------------------------
struct WcSeg { const float* src; short* dst; int K, N, ntx, start; };
struct WcArgs { WcSeg s[8]; };

__global__ __launch_bounds__(256) void wconv_all(WcArgs a) {
  __shared__ float tile[64][65];
  const int bid = blockIdx.x;
  int si = 0;
  #pragma unroll
  for (int i = 1; i < 8; ++i) if (bid >= a.s[i].start) si = i;
  const float* W = a.s[si].src;
  short* Wt = a.s[si].dst;
  const int K = a.s[si].K, N = a.s[si].N;
  const int t = bid - a.s[si].start;
  const int n0 = (t % a.s[si].ntx)*64, k0 = (t / a.s[si].ntx)*64;
  const int tid = threadIdx.x;
  for (int i = tid; i < 4096; i += 256) {
    int r = i>>6, c = i&63;
    tile[r][c] = W[(size_t)(k0+r)*N + n0 + c];
  }
  __syncthreads();
  for (int i = tid; i < 4096; i += 256) {
    int r = i>>6, c = i&63;
    Wt[(size_t)(n0+r)*K + k0 + c] = f2bf(tile[c][r]);
  }
}

// ---------------------------------------------------------------------------
// V pre-transpose: qkv[:,1536+h*64+d] -> vt[(b*H+h)*64+d][s]  (bf16)
// grid (SDIM/64, BDIM*HDIM)
// ---------------------------------------------------------------------------
__global__ __launch_bounds__(256) void vtrans_kernel(
    const short* __restrict__ qkv, short* __restrict__ vt) {
  __shared__ short t[64][72];
  const int s0 = blockIdx.x*64;
  const int bh = blockIdx.y;
  const int b = bh / HDIM, h = bh % HDIM;
  const int tid = threadIdx.x;
  for (int i = tid; i < 512; i += 256) {
    int r = i>>3, c8 = (i&7)<<3;
    *(short8*)&t[r][c8] =
        *(const short8*)&qkv[(size_t)(b*SDIM+s0+r)*2304 + 1536 + h*DHD + c8];
  }
  __syncthreads();
  for (int i = tid; i < 512; i += 256) {
    int d = i>>3, c8 = (i&7)<<3;
    short8 pk;
    #pragma unroll
    for (int j = 0; j < 8; ++j) pk[j] = t[c8+j][d];
    *(short8*)&vt[(size_t)(bh*DHD+d)*SDIM + s0 + c8] = pk;
  }
}

// ---------------------------------------------------------------------------
// h_bf = bf16(h); hn hi/lo bf16 split; x = LN(h) (fp32 + bf16)
// ---------------------------------------------------------------------------
__global__ __launch_bounds__(256) void norm_ln1_kernel(
    const float* __restrict__ h, const float* __restrict__ s,
    const float* __restrict__ bb, short* __restrict__ hb,
    short* __restrict__ hh, short* __restrict__ hl,
    float* __restrict__ x, short* __restrict__ xb) {
  int row = blockIdx.x;
  const float* hr = h + (size_t)row * EDIM;
  float v[3], s1 = 0.f, s2 = 0.f;
  #pragma unroll
  for (int t = 0; t < 3; ++t) {
    v[t] = hr[threadIdx.x + 256*t];
    s1 += v[t]; s2 += v[t]*v[t];
  }
  block_reduce_sum2(s1, s2);
  float mu  = s1 * (1.f/EDIM);
  float var = s2 * (1.f/EDIM) - mu*mu;
  float rs  = rsqrtf(var + 1e-6f);
  float invn = 1.f / (sqrtf(s2) + 1e-8f);
  #pragma unroll
  for (int t = 0; t < 3; ++t) {
    int i = threadIdx.x + 256*t;
    size_t idx = (size_t)row*EDIM + i;
    hb[idx] = f2bf(v[t]);
    float hnv = v[t]*invn;
    short hi = f2bf(hnv);
    hh[idx] = hi;
    hl[idx] = f2bf(hnv - bf2f(hi));
    float xv = (v[t]-mu)*rs*s[i] + bb[i];
    x[idx] = xv;
    xb[idx] = f2bf(xv);
  }
}

// ---------------------------------------------------------------------------
// LN -> bf16 out only
// ---------------------------------------------------------------------------
__global__ __launch_bounds__(256) void ln_bf_kernel(
    const float* __restrict__ in, const float* __restrict__ s,
    const float* __restrict__ bb, short* __restrict__ outb) {
  int row = blockIdx.x;
  const float* r = in + (size_t)row * EDIM;
  float v[3], s1 = 0.f, s2 = 0.f;
  #pragma unroll
  for (int t = 0; t < 3; ++t) {
    v[t] = r[threadIdx.x + 256*t];
    s1 += v[t]; s2 += v[t]*v[t];
  }
  block_reduce_sum2(s1, s2);
  float mu  = s1 * (1.f/EDIM);
  float var = s2 * (1.f/EDIM) - mu*mu;
  float rs  = rsqrtf(var + 1e-6f);
  #pragma unroll
  for (int t = 0; t < 3; ++t) {
    int i = threadIdx.x + 256*t;
    outb[(size_t)row*EDIM + i] = f2bf((v[t]-mu)*rs*s[i] + bb[i]);
  }
}

// ---------------------------------------------------------------------------
// bf16 MFMA GEMM, m97 single-buffer structure + XCD-chunked block swizzle.
// Tile 128 x BN (BN = 64 or 128), BK=64, 256 thr = 4 waves (2x2),
// wave tile 64 x BN/2. A [M][K] bf16, Wt [N][K] bf16. LDS [rows][64] with
// slot^(row&7) XOR swizzle, staged via global_load_lds (pre-swizzled source).
// ACT: 0 none, 2 gelu(tanh), 3 sigmoid-blend. OUTBF: bf16 vs fp32 out.
// Grid (x,y) must satisfy (gx*gy) % 8 == 0 for the bijective XCD swizzle.
// ---------------------------------------------------------------------------
template<int ACT, int OUTBF, int BN>
__global__ __launch_bounds__(256) void gemm_mfma(
    const short* __restrict__ A, const short* __restrict__ Wt,
    const float* __restrict__ bias, const float* res,
    float* Cf, short* Cb, int Cb_ld,
    const float* __restrict__ blc, const float* __restrict__ blx,
    int K, int N) {
  constexpr int NT = BN/32;              // B-frags per wave
  constexpr int BITER = BN/32;           // staging iters for B (BN*64*2B/4KB)
  __shared__ __align__(16) short As[128*64];
  __shared__ __align__(16) short Bs[BN*64];
  // XCD-chunked bijective swizzle: same-row tiles land on one XCD
  const int nwg = gridDim.x * gridDim.y;
  int bid = blockIdx.y * gridDim.x + blockIdx.x;
  bid = (bid & 7) * (nwg >> 3) + (bid >> 3);
  const int bm = (bid / gridDim.x) * 128;
  const int bn = (bid % gridDim.x) * BN;
  const int tid = threadIdx.x;
  const int w = tid>>6, lane = tid&63, l15 = lane&15, g = lane>>4;
  const int wm = (w>>1)*64, wn = (w&1)*(BN/2);
  f32x4 acc[4][NT] = {};
  for (int k0 = 0; k0 < K; k0 += 64) {
    #pragma unroll
    for (int it = 0; it < 4; ++it) {
      int p = (it*256 + tid)*16;          // byte pos in linear 16KB A-tile
      int row = p >> 7;
      int ss = ((p >> 4) & 7) ^ (row & 7);
      cp16((char*)As + it*4096 + w*1024, A + (size_t)(bm+row)*K + k0 + ss*8);
    }
    #pragma unroll
    for (int it = 0; it < BITER; ++it) {
      int p = (it*256 + tid)*16;
      int row = p >> 7;
      int ss = ((p >> 4) & 7) ^ (row & 7);
      cp16((char*)Bs + it*4096 + w*1024, Wt + (size_t)(bn+row)*K + k0 + ss*8);
    }
    __syncthreads();
    #pragma unroll
    for (int ks = 0; ks < 2; ++ks) {
      short8 af[4], bfv[NT];
      #pragma unroll
      for (int mt = 0; mt < 4; ++mt) {
        int r = wm + mt*16 + l15;
        af[mt] = *(const short8*)&As[r*64 + (((ks*4+g) ^ (r&7))*8)];
      }
      #pragma unroll
      for (int nt = 0; nt < NT; ++nt) {
        int r = wn + nt*16 + l15;
        bfv[nt] = *(const short8*)&Bs[r*64 + (((ks*4+g) ^ (r&7))*8)];
      }
      #pragma unroll
      for (int mt = 0; mt < 4; ++mt)
        #pragma unroll
        for (int nt = 0; nt < NT; ++nt)
          acc[mt][nt] = __builtin_amdgcn_mfma_f32_16x16x32_bf16(af[mt], bfv[nt], acc[mt][nt], 0, 0, 0);
    }
    __syncthreads();
  }
  #pragma unroll
  for (int mt = 0; mt < 4; ++mt) {
    #pragma unroll
    for (int nt = 0; nt < NT; ++nt) {
      #pragma unroll
      for (int reg = 0; reg < 4; ++reg) {
        int row = bm + wm + mt*16 + g*4 + reg;
        int col = bn + wn + nt*16 + l15;
        float v = acc[mt][nt][reg];
        if (bias) v += bias[col];
        if (ACT == 2) {
          float xx = v;
          float t2 = 0.7978845608028654f*(xx + 0.044715f*xx*xx*xx);
          v = 0.5f*xx*(1.f + tanhf(t2));
        }
        if (ACT == 3) {
          float gg = 1.f/(1.f + expf(-v));
          size_t ix = (size_t)row*EDIM + col;     // N == EDIM for gate
          float mv = gg*blc[ix] + (1.f-gg)*blx[ix];
          Cb[(size_t)row*Cb_ld + col] = f2bf(mv);
        } else {
          if (res) v += res[(size_t)row*N + col];
          if (OUTBF) Cb[(size_t)row*Cb_ld + col] = f2bf(v);
          else       Cf[(size_t)row*N + col] = v;
        }
      }
    }
  }
}

// ---------------------------------------------------------------------------
// dist = 1 - hn@hn^T via hi/lo bf16 split (3 MFMA products), 128x128 tiles,
// m97 single-buffer + XCD swizzle. diag = 1e9. Per-batch.
// ---------------------------------------------------------------------------
__global__ __launch_bounds__(256) void dist_mfma(
    const short* __restrict__ Hh, const short* __restrict__ Hl,
    float* __restrict__ dist) {
  __shared__ __align__(16) short Ah[128*64], Al[128*64];
  __shared__ __align__(16) short Bh[128*64], Bl[128*64];
  const int nwg = gridDim.x * gridDim.y;
  int bid = blockIdx.y * gridDim.x + blockIdx.x;
  bid = (bid & 7) * (nwg >> 3) + (bid >> 3);
  const int bm = (bid / gridDim.x) * 128;
  const int bn = (bid % gridDim.x) * 128;
  const int tid = threadIdx.x;
  const int w = tid>>6, lane = tid&63, l15 = lane&15, g = lane>>4;
  const int wm = (w>>1)*64, wn = (w&1)*64;
  f32x4 acc[4][4] = {};
  for (int k0 = 0; k0 < EDIM; k0 += 64) {
    #pragma unroll
    for (int it = 0; it < 4; ++it) {
      int p = (it*256 + tid)*16;
      int row = p >> 7;
      int ss = ((p >> 4) & 7) ^ (row & 7);
      size_t ga = (size_t)(bm+row)*EDIM + k0 + ss*8;
      size_t gb = (size_t)(bn+row)*EDIM + k0 + ss*8;
      cp16((char*)Ah + it*4096 + w*1024, Hh + ga);
      cp16((char*)Al + it*4096 + w*1024, Hl + ga);
      cp16((char*)Bh + it*4096 + w*1024, Hh + gb);
      cp16((char*)Bl + it*4096 + w*1024, Hl + gb);
    }
    __syncthreads();
    #pragma unroll
    for (int ks = 0; ks < 2; ++ks) {
      short8 ah[4], al[4], bh[4], bl[4];
      #pragma unroll
      for (int mt = 0; mt < 4; ++mt) {
        int r = wm + mt*16 + l15;
        int o = r*64 + (((ks*4+g) ^ (r&7))*8);
        ah[mt] = *(const short8*)&Ah[o];
        al[mt] = *(const short8*)&Al[o];
      }
      #pragma unroll
      for (int nt = 0; nt < 4; ++nt) {
        int r = wn + nt*16 + l15;
        int o = r*64 + (((ks*4+g) ^ (r&7))*8);
        bh[nt] = *(const short8*)&Bh[o];
        bl[nt] = *(const short8*)&Bl[o];
      }
      #pragma unroll
      for (int mt = 0; mt < 4; ++mt)
        #pragma unroll
        for (int nt = 0; nt < 4; ++nt) {
          acc[mt][nt] = __builtin_amdgcn_mfma_f32_16x16x32_bf16(ah[mt], bh[nt], acc[mt][nt], 0, 0, 0);
          acc[mt][nt] = __builtin_amdgcn_mfma_f32_16x16x32_bf16(ah[mt], bl[nt], acc[mt][nt], 0, 0, 0);
          acc[mt][nt] = __builtin_amdgcn_mfma_f32_16x16x32_bf16(al[mt], bh[nt], acc[mt][nt], 0, 0, 0);
        }
    }
    __syncthreads();
  }
  #pragma unroll
  for (int mt = 0; mt < 4; ++mt) {
    #pragma unroll
    for (int nt = 0; nt < 4; ++nt) {
      #pragma unroll
      for (int reg = 0; reg < 4; ++reg) {
        int row = bm + wm + mt*16 + g*4 + reg;
        int col = bn + wn + nt*16 + l15;
        float v = 1.f - acc[mt][nt][reg];
        if (row == col) v = 1e9f;
        dist[(size_t)row*SDIM + col] = v;
      }
    }
  }
}

// ---------------------------------------------------------------------------
// per-row top-16 (stable ties -> smaller idx), softmax(-nd), combined.
// values cached in registers; per pass only a shuffle-reduce + owner rescan.
// ---------------------------------------------------------------------------
__global__ __launch_bounds__(256) void topk_kernel(
    const float* __restrict__ dist, const float* __restrict__ topob,
    float* __restrict__ combb) {
  int s = blockIdx.x;
  __shared__ float wbv[4];
  __shared__ int   wbi[4];
  __shared__ float nd[KNN];
  __shared__ int   nidx[KNN];
  __shared__ float wts[KNN];
  const int tid = threadIdx.x, lane = tid & 63, wid = tid >> 6;
  const float* drow = dist + (size_t)s*SDIM;
  float lv[8];
  float best = 3e38f; int bidx = 1<<30;
  #pragma unroll
  for (int j = 0; j < 8; ++j) {
    int i = tid + j*256;
    float v = drow[i];
    lv[j] = v;
    if (v < best) { best = v; bidx = i; }
  }
  for (int pass = 0; pass < KNN; ++pass) {
    float bv = best; int bi = bidx;
    #pragma unroll
    for (int off = 32; off > 0; off >>= 1) {
      float ov = __shfl_xor(bv, off);
      int   oi = __shfl_xor(bi, off);
      if (ov < bv || (ov == bv && oi < bi)) { bv = ov; bi = oi; }
    }
    if (lane == 0) { wbv[wid] = bv; wbi[wid] = bi; }
    __syncthreads();
    if (tid == 0) {
      float fv = wbv[0]; int fi = wbi[0];
      #pragma unroll
      for (int q2 = 1; q2 < 4; ++q2)
        if (wbv[q2] < fv || (wbv[q2] == fv && wbi[q2] < fi)) { fv = wbv[q2]; fi = wbi[q2]; }
      nd[pass] = fv; nidx[pass] = fi;
    }
    __syncthreads();
    int wi = nidx[pass];
    if ((wi & 255) == tid) {
      int jj = wi >> 8;
      #pragma unroll
      for (int j = 0; j < 8; ++j) if (j == jj) lv[j] = 3e38f;
      best = 3e38f; bidx = 1<<30;
      #pragma unroll
      for (int j = 0; j < 8; ++j)
        if (lv[j] < best) { best = lv[j]; bidx = tid + j*256; }
    }
    __syncthreads();
  }
  if (tid == 0) {
    float m = -nd[0];
    for (int k2 = 1; k2 < KNN; ++k2) m = fmaxf(m, -nd[k2]);
    float ssum = 0.f;
    for (int k2 = 0; k2 < KNN; ++k2) { float e = expf(-nd[k2] - m); wts[k2] = e; ssum += e; }
    float inv = 1.f/ssum;
    for (int k2 = 0; k2 < KNN; ++k2) wts[k2] *= inv;
  }
  __syncthreads();
  if (tid < TDIM) {
    float acc = topob[(size_t)s*TDIM + tid];
    #pragma unroll
    for (int k2 = 0; k2 < KNN; ++k2) acc += wts[k2]*topob[(size_t)nidx[k2]*TDIM + tid];
    combb[(size_t)s*TDIM + tid] = acc;
  }
}

// ---------------------------------------------------------------------------
// fused topo-MLP per row (fp32), writes pf as bf16 into cat[:, 768:896]
// ---------------------------------------------------------------------------
__global__ __launch_bounds__(256) void topo_mlp_kernel(
    const float* __restrict__ comb,
    const float* __restrict__ W1, const float* __restrict__ b1,
    const float* __restrict__ W2, const float* __restrict__ b2,
    const float* __restrict__ lns, const float* __restrict__ lnb,
    const float* __restrict__ Wp1, const float* __restrict__ bp1,
    const float* __restrict__ Wp2, const float* __restrict__ bp2,
    short* __restrict__ cat) {
  int row = blockIdx.x;
  __shared__ float c[TDIM], a1[2*TDIM], t2[TDIM];
  __shared__ float red[8];
  const int tid = threadIdx.x;
  if (tid < TDIM) c[tid] = comb[(size_t)row*TDIM + tid];
  __syncthreads();
  {
    float a = b1[tid];
    for (int i = 0; i < TDIM; ++i) a += c[i]*W1[i*2*TDIM + tid];
    a1[tid] = fmaxf(a, 0.f);
  }
  __syncthreads();
  float tval = 0.f;
  if (tid < TDIM) {
    float a = b2[tid];
    for (int i = 0; i < 2*TDIM; ++i) a += a1[i]*W2[i*TDIM + tid];
    tval = a;
  }
  float s1 = (tid < TDIM) ? tval : 0.f;
  float s2 = (tid < TDIM) ? tval*tval : 0.f;
  #pragma unroll
  for (int off = 32; off > 0; off >>= 1) { s1 += __shfl_xor(s1, off); s2 += __shfl_xor(s2, off); }
  if ((tid & 63) == 0) { red[tid>>6] = s1; red[4 + (tid>>6)] = s2; }
  __syncthreads();
  s1 = red[0]+red[1]+red[2]+red[3];
  s2 = red[4]+red[5]+red[6]+red[7];
  float mu  = s1 * (1.f/TDIM);
  float var = s2 * (1.f/TDIM) - mu*mu;
  float rs  = rsqrtf(var + 1e-6f);
  if (tid < TDIM) t2[tid] = (tval - mu)*rs*lns[tid] + lnb[tid];
  __syncthreads();
  if (tid < TDIM) {
    float a = bp1[tid];
    for (int i = 0; i < TDIM; ++i) a += t2[i]*Wp1[i*TDIM + tid];
    a1[tid] = fmaxf(a, 0.f);
  }
  __syncthreads();
  if (tid < TDIM) {
    float a = bp2[tid];
    for (int i = 0; i < TDIM; ++i) a += a1[i]*Wp2[i*TDIM + tid];
    cat[(size_t)row*896 + 768 + tid] = f2bf(a);
  }
}

// ---------------------------------------------------------------------------
// MFMA flash attention v3: swapped QK^T (S^T = mfma(K,Q)) -> per-lane q-row,
// in-lane softmax (log2 domain, exp2), defer-max (THR=8), packed P stores.
// grid (S/64, H, B), 256 thr = 4 waves; wave owns 16 q rows; KT=128.
// ---------------------------------------------------------------------------
__global__ __launch_bounds__(256) void attn_mfma(
    const short* __restrict__ qkv, const short* __restrict__ vtb,
    const int* __restrict__ maskp,
    float* __restrict__ ctx, short* __restrict__ ctxb) {
  __shared__ __align__(16) short Ks[128*64];     // [krow][d]   8-slot swizzle
  __shared__ __align__(16) short Vs[64*128];     // [d][krow]  16-slot swizzle
  __shared__ __align__(16) short Ps[4*16*128];   // per-wave [q][k], slot^((q&7)<<1)
  __shared__ float Ms[128];
  const float SCL = 0.18033688011112042f;        // 0.125 * log2(e)
  const float MASKVAL = -14426.950408889634f;    // -10000 * log2(e)
  const int qb0 = blockIdx.x*64;
  const int hh = blockIdx.y, b = blockIdx.z;
  const int bh = b*HDIM + hh;
  const int tid = threadIdx.x;
  const int w = tid>>6, lane = tid&63, l15 = lane&15, g = lane>>4;
  short8 qf[2];
  {
    size_t rbase = (size_t)(b*SDIM + qb0 + w*16 + l15)*2304 + hh*DHD;
    qf[0] = *(const short8*)&qkv[rbase + g*8];
    qf[1] = *(const short8*)&qkv[rbase + 32 + g*8];
  }
  f32x4 acc[4] = {};
  float m_run = -1e30f, l_run = 0.f;
  char* PsW = (char*)Ps + w*4096 + l15*256;      // this lane's q-row base
  const int swz = (l15 & 7) << 1;                 // slot XOR (8B slots)
  for (int kt = 0; kt < SDIM; kt += 128) {
    // K tile: 128 rows x 64 d
    #pragma unroll
    for (int it = 0; it < 4; ++it) {
      int t = it*256 + tid;
      int row = t>>3, slot = t&7, ss = slot ^ (row&7);
      cp16((char*)Ks + it*4096 + w*1024,
           qkv + (size_t)(b*SDIM+kt+row)*2304 + 768 + hh*DHD + ss*8);
    }
    // V^T tile: 64 d-rows x 128 s
    #pragma unroll
    for (int it = 0; it < 4; ++it) {
      int t = it*256 + tid;
      int row = t>>4, slot = t&15, ss = slot ^ (row&15);
      cp16((char*)Vs + it*4096 + w*1024,
           vtb + (size_t)(bh*DHD+row)*SDIM + kt + ss*8);
    }
    if (tid < 128) Ms[tid] = (float)maskp[b*SDIM + kt + tid];
    __syncthreads();
    // S^T = K @ Q^T : lane holds k = ct*16+g*4+reg, q = l15
    f32x4 s[8] = {};
    #pragma unroll
    for (int ks = 0; ks < 2; ++ks) {
      #pragma unroll
      for (int ct = 0; ct < 8; ++ct) {
        int r = ct*16 + l15;
        short8 kb8 = *(const short8*)&Ks[r*64 + (((ks*4+g) ^ (r&7))*8)];
        s[ct] = __builtin_amdgcn_mfma_f32_16x16x32_bf16(kb8, qf[ks], s[ct], 0, 0, 0);
      }
    }
    // scale (log2 domain) + mask + row max
    float rm = -1e30f;
    #pragma unroll
    for (int ct = 0; ct < 8; ++ct) {
      float4 mk = *(const float4*)&Ms[ct*16 + g*4];
      float v0 = s[ct][0]*SCL; if (mk.x == 0.f) v0 = MASKVAL;
      float v1 = s[ct][1]*SCL; if (mk.y == 0.f) v1 = MASKVAL;
      float v2 = s[ct][2]*SCL; if (mk.z == 0.f) v2 = MASKVAL;
      float v3 = s[ct][3]*SCL; if (mk.w == 0.f) v3 = MASKVAL;
      s[ct][0] = v0; s[ct][1] = v1; s[ct][2] = v2; s[ct][3] = v3;
      rm = fmaxf(rm, fmaxf(fmaxf(v0, v1), fmaxf(v2, v3)));
    }
    rm = fmaxf(rm, __shfl_xor(rm, 16));
    rm = fmaxf(rm, __shfl_xor(rm, 32));
    // defer-max: only rescale when some row grew past THR (=8/ln2)
    if (__any(rm > m_run + 11.5415603f)) {
      float mnew = fmaxf(m_run, rm);
      float corr = exp2_fast(m_run - mnew);
      l_run *= corr;
      #pragma unroll
      for (int reg = 0; reg < 4; ++reg) {
        float cq = __shfl(corr, (g<<4) | (g*4 + reg));
        #pragma unroll
        for (int dt = 0; dt < 4; ++dt) acc[dt][reg] *= cq;
      }
      m_run = mnew;
    }
    // P = exp2(s - m), in-lane sum, packed store to per-wave P buffer
    float rs = 0.f;
    #pragma unroll
    for (int ct = 0; ct < 8; ++ct) {
      float p0 = exp2_fast(s[ct][0] - m_run);
      float p1 = exp2_fast(s[ct][1] - m_run);
      float p2 = exp2_fast(s[ct][2] - m_run);
      float p3 = exp2_fast(s[ct][3] - m_run);
      rs += (p0 + p1) + (p2 + p3);
      u32x2 pk;
      pk.x = cvt_pk_bf16(p0, p1);
      pk.y = cvt_pk_bf16(p2, p3);
      int slot = ct*4 + g;                       // k-quad index
      *(u32x2*)(PsW + ((slot ^ swz) << 3)) = pk;
    }
    rs += __shfl_xor(rs, 16);
    rs += __shfl_xor(rs, 32);
    l_run += rs;
    // ctx += P @ V : P read back as A-frag from per-wave buffer
    #pragma unroll
    for (int ks2 = 0; ks2 < 4; ++ks2) {
      int s0 = ks2*8 + g*2;
      short8 pa = *(const short8*)(PsW + ((s0 ^ swz) << 3));
      #pragma unroll
      for (int dt = 0; dt < 4; ++dt) {
        int r = dt*16 + l15;
        short8 vb8 = *(const short8*)&Vs[r*128 + (((ks2*4+g) ^ (r&15))*8)];
        acc[dt] = __builtin_amdgcn_mfma_f32_16x16x32_bf16(pa, vb8, acc[dt], 0, 0, 0);
      }
    }
    __syncthreads();
  }
  float invq[4];
  #pragma unroll
  for (int reg = 0; reg < 4; ++reg)
    invq[reg] = 1.f / __shfl(l_run, (g<<4) | (g*4 + reg));
  #pragma unroll
  for (int dt = 0; dt < 4; ++dt) {
    #pragma unroll
    for (int reg = 0; reg < 4; ++reg) {
      int row = b*SDIM + qb0 + w*16 + g*4 + reg;
      float v = acc[dt][reg]*invq[reg];
      ctx [(size_t)row*EDIM + hh*DHD + dt*16 + l15] = v;
      ctxb[(size_t)row*896  + hh*DHD + dt*16 + l15] = f2bf(v);
    }
  }
}

// ---------------------------------------------------------------------------
extern "C" void kernel_launch(void* const* d_in, const int* in_sizes, int n_in,
                              void* d_out, int out_size, void* d_ws, size_t ws_size,
                              hipStream_t stream) {
  const float* h      = (const float*)d_in[0];
  const int*   mask   = (const int*)  d_in[1];
  const float* W_topo = (const float*)d_in[2];
  const float* b_topo = (const float*)d_in[3];
  const float* W_m1   = (const float*)d_in[4];
  const float* b_m1   = (const float*)d_in[5];
  const float* W_m2   = (const float*)d_in[6];
  const float* b_m2   = (const float*)d_in[7];
  const float* ln_t_s = (const float*)d_in[8];
  const float* ln_t_b = (const float*)d_in[9];
  const float* W_p1   = (const float*)d_in[10];
  const float* b_p1   = (const float*)d_in[11];
  const float* W_p2   = (const float*)d_in[12];
  const float* b_p2   = (const float*)d_in[13];
  const float* ln1_s  = (const float*)d_in[14];
  const float* ln1_b  = (const float*)d_in[15];
  const float* Wq     = (const float*)d_in[16];
  const float* Wk     = (const float*)d_in[17];
  const float* Wv     = (const float*)d_in[18];
  const float* W_gate = (const float*)d_in[19];
  const float* b_gate = (const float*)d_in[20];
  const float* W_o    = (const float*)d_in[21];
  const float* b_o    = (const float*)d_in[22];
  const float* ln2_s  = (const float*)d_in[23];
  const float* ln2_b  = (const float*)d_in[24];
  const float* W_f1   = (const float*)d_in[25];
  const float* b_f1   = (const float*)d_in[26];
  const float* W_f2   = (const float*)d_in[27];
  const float* b_f2   = (const float*)d_in[28];
  float* out = (float*)d_out;

  // ---- workspace layout (~90 MB) ----
  const size_t R = (size_t)BS*EDIM;    // 3,145,728 elements
  short* wt_topo = (short*)d_ws;                       // [128][768]
  short* wt_qkv  = wt_topo + (size_t)128*768;          // [2304][768]
  short* wt_g    = wt_qkv  + (size_t)2304*768;         // [768][896]
  short* wt_o    = wt_g    + (size_t)768*896;          // [768][768]
  short* wt_f1   = wt_o    + (size_t)768*768;          // [3072][768]
  short* wt_f2   = wt_f1   + (size_t)3072*768;         // [768][3072]
  short* regA    = wt_f2   + (size_t)768*3072;         // R: h_bf -> mixb
  short* regBCE  = regA + R;                           // 3R: hn_hi|hn_lo|E -> qkv
  short* regD    = regBCE + 3*R;                       // R: x_bf -> y_bf
  short* cat     = regD + R;                           // BS*896: [ctx_bf | pf_bf]
  float* xf      = (float*)(cat + (size_t)BS*896);     // R fp32: post-LN x
  float* Ff      = xf + R;                             // 16.8MB: dist / ctx / ybuf
  short* vtb     = (short*)(Ff + (size_t)SDIM*SDIM);   // R shorts: V^T per (b,h)

  short* h_bf  = regA;
  short* mixb  = regA;
  short* hn_hi = regBCE;
  short* hn_lo = regBCE + R;
  float* topo  = (float*)(regBCE + 2*R);
  float* comb  = topo + (size_t)BS*TDIM;
  short* qkvb  = regBCE;
  short* x_bf  = regD;
  short* y_bf  = regD;
  float* dbuf  = Ff;
  float* ctxf  = Ff;
  short* ybuf  = (short*)Ff;

  // P0: all weight transposes+converts in ONE launch (1920 tiles)
  WcArgs wa;
  wa.s[0] = {W_topo, wt_topo,                    EDIM, TDIM,  TDIM/64, 0};
  wa.s[1] = {Wq,     wt_qkv,                     EDIM, EDIM,  EDIM/64, 24};
  wa.s[2] = {Wk,     wt_qkv + (size_t)768*768,   EDIM, EDIM,  EDIM/64, 168};
  wa.s[3] = {Wv,     wt_qkv + (size_t)1536*768,  EDIM, EDIM,  EDIM/64, 312};
  wa.s[4] = {W_gate, wt_g,                       896,  EDIM,  EDIM/64, 456};
  wa.s[5] = {W_o,    wt_o,                       EDIM, EDIM,  EDIM/64, 624};
  wa.s[6] = {W_f1,   wt_f1,                      EDIM, FDIM,  FDIM/64, 768};
  wa.s[7] = {W_f2,   wt_f2,                      FDIM, EDIM,  EDIM/64, 1344};
  wconv_all<<<1920, 256, 0, stream>>>(wa);
  // P1: h_bf + hn hi/lo + LN1 (fp32 + bf16)
  norm_ln1_kernel<<<BS, 256, 0, stream>>>(h, ln1_s, ln1_b, h_bf, hn_hi, hn_lo, xf, x_bf);
  // P2: topo = h @ W_topo + b_topo (fp32 out; grid 64)
  gemm_mfma<0,0,64><<<dim3(TDIM/64, BS/128), 256, 0, stream>>>(
      h_bf, wt_topo, b_topo, nullptr, topo, nullptr, 0, nullptr, nullptr, EDIM, TDIM);
  // P3: per-batch dist + topk + combined
  for (int b = 0; b < BDIM; ++b) {
    dist_mfma<<<dim3(SDIM/128, SDIM/128), 256, 0, stream>>>(
        hn_hi + (size_t)b*SDIM*EDIM, hn_lo + (size_t)b*SDIM*EDIM, dbuf);
    topk_kernel<<<SDIM, 256, 0, stream>>>(
        dbuf, topo + (size_t)b*SDIM*TDIM, comb + (size_t)b*SDIM*TDIM);
  }
  // P4: topo MLP -> pf bf16 into cat[:,768:]
  topo_mlp_kernel<<<BS, 256, 0, stream>>>(comb, W_m1, b_m1, W_m2, b_m2,
                                          ln_t_s, ln_t_b, W_p1, b_p1, W_p2, b_p2, cat);
  // P5: fused QKV (N=2304, bf16 out; grid 576)
  gemm_mfma<0,1,128><<<dim3(2304/128, BS/128), 256, 0, stream>>>(
      x_bf, wt_qkv, nullptr, nullptr, nullptr, qkvb, 2304, nullptr, nullptr, EDIM, 2304);
  // P5b: V pre-transpose for attention
  vtrans_kernel<<<dim3(SDIM/64, BDIM*HDIM), 256, 0, stream>>>(qkvb, vtb);
  // P6: attention -> ctx fp32 (Ff) + ctx bf16 (cat[:,0:768])
  attn_mfma<<<dim3(SDIM/64, HDIM, BDIM), 256, 0, stream>>>(qkvb, vtb, mask, ctxf, cat);
  // P7: gate GEMM (K=896) with fused sigmoid-blend -> mixb bf16 (grid 384)
  gemm_mfma<3,1,64><<<dim3(EDIM/64, BS/128), 256, 0, stream>>>(
      cat, wt_g, b_gate, nullptr, nullptr, mixb, EDIM, ctxf, xf, 896, EDIM);
  // P8: h2 = h + mix @ W_o + b_o -> out (grid 384)
  gemm_mfma<0,0,64><<<dim3(EDIM/64, BS/128), 256, 0, stream>>>(
      mixb, wt_o, b_o, h, out, nullptr, 0, nullptr, nullptr, EDIM, EDIM);
  // P9: y = LN2(h2) -> y_bf
  ln_bf_kernel<<<BS, 256, 0, stream>>>(out, ln2_s, ln2_b, y_bf);
  // P10: yF = gelu(y @ W_f1 + b_f1) -> ybuf bf16 (grid 768)
  gemm_mfma<2,1,128><<<dim3(FDIM/128, BS/128), 256, 0, stream>>>(
      y_bf, wt_f1, b_f1, nullptr, nullptr, ybuf, FDIM, nullptr, nullptr, EDIM, FDIM);
  // P11: out = h2 + yF @ W_f2 + b_f2 (in place; grid 384)
  gemm_mfma<0,0,64><<<dim3(EDIM/64, BS/128), 256, 0, stream>>>(
      ybuf, wt_f2, b_f2, out, out, nullptr, 0, nullptr, nullptr, FDIM, EDIM);
}